// Round 18
// baseline (675.327 us; speedup 1.0000x reference)
//
#include <hip/hip_runtime.h>

#define N_NODES 100000
#define N_EDGES 1600000
#define D 128
#define BN_EPS 1e-5f
#define N_GB ((N_NODES + 63) / 64)      // 1563 gemm tiles
#define NPART 8
#define FILL_BLOCKS 2048
#define NODES_PER_PART (N_NODES / NPART)  // 12500 exact
#define CAP 48                            // bucket capacity (mean deg 16)
#define PCAP 210000                       // per-partition queue capacity (~24 sigma)
#define NPB 250                           // nodes per fill3 block (12500/250 = 50 chunks)
#define FILL3_BLOCKS (NPART * 50)         // 400

typedef short bf16x8 __attribute__((ext_vector_type(8)));
typedef float f32x4 __attribute__((ext_vector_type(4)));

__device__ inline unsigned short f32_to_bf16_rne(float f) {
    unsigned u = __builtin_bit_cast(unsigned, f);
    u += 0x7fffu + ((u >> 16) & 1u);
    return (unsigned short)(u >> 16);
}
__device__ inline float bf16lo_to_f32(unsigned v) { return __builtin_bit_cast(float, v << 16); }
__device__ inline float bf16hi_to_f32(unsigned v) { return __builtin_bit_cast(float, v & 0xffff0000u); }

__device__ inline void gload_lds16(const void* g, void* l) {
    __builtin_amdgcn_global_load_lds((const __attribute__((address_space(1))) unsigned*)g,
                                     (__attribute__((address_space(3))) unsigned*)l, 16, 0, 0);
}

// ---------------- prep: streaming conversions + gcur zeroing ----------------

__global__ __launch_bounds__(256) void k_prep(const float* __restrict__ x_in,
                                              const float* __restrict__ Wl, const float* __restrict__ Wr,
                                              unsigned short* __restrict__ xhi,
                                              unsigned short* __restrict__ wl_hi, unsigned short* __restrict__ wl_lo,
                                              unsigned short* __restrict__ wr_hi, unsigned short* __restrict__ wr_lo,
                                              int* __restrict__ gcur) {
    for (int idx = blockIdx.x * 256 + threadIdx.x; idx < N_NODES * 32; idx += FILL_BLOCKS * 256) {
        float4 v = ((const float4*)x_in)[idx];
        uint2 p;
        p.x = (unsigned)f32_to_bf16_rne(v.x) | ((unsigned)f32_to_bf16_rne(v.y) << 16);
        p.y = (unsigned)f32_to_bf16_rne(v.z) | ((unsigned)f32_to_bf16_rne(v.w) << 16);
        ((uint2*)xhi)[idx] = p;
    }
    for (int i = blockIdx.x * 256 + threadIdx.x; i < 2 * 3 * D * D; i += FILL_BLOCKS * 256) {
        const float* srcp = (i < 3 * D * D) ? Wl : Wr;
        int j = (i < 3 * D * D) ? i : i - 3 * D * D;
        float w = srcp[j];
        unsigned short h = f32_to_bf16_rne(w);
        float rem = w - bf16lo_to_f32((unsigned)h);
        if (i < 3 * D * D) { wl_hi[j] = h; wl_lo[j] = f32_to_bf16_rne(rem); }
        else               { wr_hi[j] = h; wr_lo[j] = f32_to_bf16_rne(rem); }
    }
    if (blockIdx.x == 0 && threadIdx.x < NPART) gcur[threadIdx.x] = 0;
}

// ---------------- pass A: split edges into 8 per-partition queues ----------------
// Reads dst+src ONCE. Pairs packed (d_local<<17)|s  (s < 2^17, d_local < 2^15).
__global__ __launch_bounds__(256) void k_split(const int* __restrict__ src, const int* __restrict__ dst,
                                               int* __restrict__ gcur, unsigned* __restrict__ pairbuf) {
    __shared__ int cnt[NPART];
    __shared__ int base[NPART];
    const int t = threadIdx.x;
    if (t < NPART) cnt[t] = 0;
    __syncthreads();
    unsigned pk[4];
    int part[4], pos[4];
    const int e0 = blockIdx.x * 256 + t;
#pragma unroll
    for (int r = 0; r < 4; r++) {
        int e = e0 + r * (FILL_BLOCKS * 256);
        part[r] = -1;
        if (e < N_EDGES) {
            int d = dst[e];
            int s = src[e];
            int p = d / NODES_PER_PART;
            part[r] = p;
            pos[r] = atomicAdd(&cnt[p], 1);
            pk[r] = ((unsigned)(d - p * NODES_PER_PART) << 17) | (unsigned)s;
        }
    }
    __syncthreads();
    if (t < NPART) base[t] = atomicAdd(&gcur[t], cnt[t]);
    __syncthreads();
#pragma unroll
    for (int r = 0; r < 4; r++) {
        if (part[r] >= 0) {
            unsigned idx = (unsigned)(base[part[r]] + pos[r]);
            if (idx < PCAP) pairbuf[(size_t)part[r] * PCAP + idx] = pk[r];
        }
    }
}

// ---------------- pass B: LDS-assembled bucket fill ----------------
// Block (p, c) owns 250 nodes; scans queue p (L2-resident, 50x redundant read),
// assembles buckets in LDS, then writes colidx as FULL contiguous 192B runs and
// cursor as full lines. Every output line written exactly once by one block ->
// immune to cross-XCD line ping-pong (R17: scattered 4B stores gave 10x write amp
// even with L2-resident inputs).
__global__ __launch_bounds__(256) void k_fill3(const unsigned* __restrict__ pairbuf,
                                               const int* __restrict__ gcur,
                                               int* __restrict__ cursor, int* __restrict__ colidx) {
    __shared__ int lcnt[NPB];
    __shared__ int lbuf[NPB * CAP];  // 48 KB
    const int t = threadIdx.x;
    const int p = blockIdx.x & (NPART - 1);
    const int c = blockIdx.x >> 3;          // 0..49
    const int nbase = c * NPB;              // local node base within partition
    const int gbase = p * NODES_PER_PART + nbase;

    for (int i = t; i < NPB; i += 256) lcnt[i] = 0;
    __syncthreads();

    int m = gcur[p]; if (m > PCAP) m = PCAP;
    const unsigned* pb = pairbuf + (size_t)p * PCAP;
    for (int i = t; i < m; i += 256) {
        unsigned pk = pb[i];
        int r = (int)(pk >> 17) - nbase;
        if ((unsigned)r < NPB) {
            int pos = atomicAdd(&lcnt[r], 1);
            if (pos < CAP) lbuf[r * CAP + pos] = (int)(pk & 0x1FFFFu);
        }
    }
    __syncthreads();

    // write colidx: NPB*CAP ints = 3000 uint4, contiguous, every byte written once
    uint4* dst4 = (uint4*)(colidx + (size_t)gbase * CAP);
    const uint4* src4 = (const uint4*)lbuf;
    for (int s4 = t; s4 < NPB * CAP / 4; s4 += 256) dst4[s4] = src4[s4];
    // cursor: contiguous 250 ints (true degree, k_agg clamps at CAP)
    for (int i = t; i < NPB; i += 256) cursor[gbase + i] = lcnt[i];
}

// ---------------- per-layer kernels ----------------

// mean aggregation: one wave per node (high occupancy — NOT fused with MFMA
// kernel per R10 lesson). colidx bucket register-cached, gathers uint4.
__global__ __launch_bounds__(256) void k_agg(const unsigned short* __restrict__ xhi,
                                             const int* __restrict__ cursor, const int* __restrict__ colidx,
                                             unsigned short* __restrict__ agghi) {
    const int wid = threadIdx.x >> 6;
    const int l = threadIdx.x & 63;
    const int n = blockIdx.x * 4 + wid;
    if (n >= N_NODES) return;
    const int degree = cursor[n];
    const int b = n * CAP;
    const int e = b + (degree < CAP ? degree : CAP);
    const int c8 = l & 15;   // 16B channel slice
    const int g = l >> 4;    // row-group 0..3
    const size_t coff = (size_t)c8 * 16;

    float acc[8];
#pragma unroll
    for (int k = 0; k < 8; k++) acc[k] = 0.f;

    int i = b;
    while (i < e) {
        int chunk = e - i; if (chunk > 64) chunk = 64;
        int myE = colidx[i + (l < chunk ? l : chunk - 1)];
        int j = 0;
        for (; j + 8 <= chunk; j += 8) {
            int s0 = __shfl(myE, j + g);
            int s1 = __shfl(myE, j + 4 + g);
            uint4 v0 = *(const uint4*)((const char*)xhi + (size_t)s0 * 256 + coff);
            uint4 v1 = *(const uint4*)((const char*)xhi + (size_t)s1 * 256 + coff);
            acc[0] += bf16lo_to_f32(v0.x); acc[1] += bf16hi_to_f32(v0.x);
            acc[2] += bf16lo_to_f32(v0.y); acc[3] += bf16hi_to_f32(v0.y);
            acc[4] += bf16lo_to_f32(v0.z); acc[5] += bf16hi_to_f32(v0.z);
            acc[6] += bf16lo_to_f32(v0.w); acc[7] += bf16hi_to_f32(v0.w);
            acc[0] += bf16lo_to_f32(v1.x); acc[1] += bf16hi_to_f32(v1.x);
            acc[2] += bf16lo_to_f32(v1.y); acc[3] += bf16hi_to_f32(v1.y);
            acc[4] += bf16lo_to_f32(v1.z); acc[5] += bf16hi_to_f32(v1.z);
            acc[6] += bf16lo_to_f32(v1.w); acc[7] += bf16hi_to_f32(v1.w);
        }
        for (; j + 4 <= chunk; j += 4) {
            int s0 = __shfl(myE, j + g);
            uint4 v0 = *(const uint4*)((const char*)xhi + (size_t)s0 * 256 + coff);
            acc[0] += bf16lo_to_f32(v0.x); acc[1] += bf16hi_to_f32(v0.x);
            acc[2] += bf16lo_to_f32(v0.y); acc[3] += bf16hi_to_f32(v0.y);
            acc[4] += bf16lo_to_f32(v0.z); acc[5] += bf16hi_to_f32(v0.z);
            acc[6] += bf16lo_to_f32(v0.w); acc[7] += bf16hi_to_f32(v0.w);
        }
        if (j < chunk) {
            int idx = j + g;
            int s0 = __shfl(myE, idx < chunk ? idx : chunk - 1);
            if (idx < chunk) {
                uint4 v0 = *(const uint4*)((const char*)xhi + (size_t)s0 * 256 + coff);
                acc[0] += bf16lo_to_f32(v0.x); acc[1] += bf16hi_to_f32(v0.x);
                acc[2] += bf16lo_to_f32(v0.y); acc[3] += bf16hi_to_f32(v0.y);
                acc[4] += bf16lo_to_f32(v0.z); acc[5] += bf16hi_to_f32(v0.z);
                acc[6] += bf16lo_to_f32(v0.w); acc[7] += bf16hi_to_f32(v0.w);
            }
        }
        i += chunk;
    }
#pragma unroll
    for (int k = 0; k < 8; k++) {
        acc[k] += __shfl_xor(acc[k], 16);
        acc[k] += __shfl_xor(acc[k], 32);
    }
    if (g == 0) {
        float idg = 1.0f / fmaxf((float)degree, 1.0f);
        uint4 p;
        p.x = (unsigned)f32_to_bf16_rne(acc[0] * idg) | ((unsigned)f32_to_bf16_rne(acc[1] * idg) << 16);
        p.y = (unsigned)f32_to_bf16_rne(acc[2] * idg) | ((unsigned)f32_to_bf16_rne(acc[3] * idg) << 16);
        p.z = (unsigned)f32_to_bf16_rne(acc[4] * idg) | ((unsigned)f32_to_bf16_rne(acc[5] * idg) << 16);
        p.w = (unsigned)f32_to_bf16_rne(acc[6] * idg) | ((unsigned)f32_to_bf16_rne(acc[7] * idg) << 16);
        *(uint4*)((char*)agghi + (size_t)n * 256 + coff) = p;
    }
}

// h(bf16) = agg @ Wl^T + bl + x @ Wr^T via MFMA.
// LDS tiles fragment-major (conflict-free); W frags pinned in VGPRs.
// BN partials per-block (no atomics). h aliases agg_hi (rows staged to LDS first).
__global__ __launch_bounds__(256, 2) void k_gemm(
    const unsigned short* __restrict__ agg_hi, const unsigned short* __restrict__ x_hi,
    const unsigned short* __restrict__ wl_hi, const unsigned short* __restrict__ wl_lo,
    const unsigned short* __restrict__ wr_hi, const unsigned short* __restrict__ wr_lo,
    const float* __restrict__ bl, unsigned short* __restrict__ h, float* __restrict__ partial) {
    __shared__ char lds[32768];  // 32 chunks x 1KB: [0..16K) agg frags, [16K..32K) x frags
    const int t = threadIdx.x;
    const int w = t >> 6;
    const int l = t & 63;
    const int lr = l & 15;
    const int lg = l >> 4;
    const int base = blockIdx.x * 64;
    const int j0 = w * 32;

    {
#pragma unroll
        for (int i = 0; i < 8; i++) {
            int c = w * 8 + i;
            int ci = c & 15;
            int m = ci >> 2, kk = ci & 3;
            int n = base + m * 16 + lr;
            if (n > N_NODES - 1) n = N_NODES - 1;
            size_t goff = (size_t)n * 256 + kk * 64 + lg * 16;
            const char* srcp = ((c & 16) ? (const char*)x_hi : (const char*)agg_hi) + goff;
            gload_lds16(srcp, lds + c * 1024);
        }
    }

    f32x4 acc[4][2];
#pragma unroll
    for (int m = 0; m < 4; m++)
#pragma unroll
        for (int f = 0; f < 2; f++) acc[m][f] = (f32x4){0.f, 0.f, 0.f, 0.f};

#pragma unroll
    for (int seg = 0; seg < 2; seg++) {
        const unsigned short* WH = seg ? wr_hi : wl_hi;
        const unsigned short* WLo = seg ? wr_lo : wl_lo;
        bf16x8 wh[4][2], wlo[4][2];
#pragma unroll
        for (int kk = 0; kk < 4; kk++)
#pragma unroll
            for (int f = 0; f < 2; f++) {
                size_t wo = (size_t)(j0 + f * 16 + lr) * D + kk * 32 + lg * 8;
                wh[kk][f] = *(const bf16x8*)(WH + wo);
                wlo[kk][f] = *(const bf16x8*)(WLo + wo);
            }
        asm volatile("" :: "v"(wh[0][0]), "v"(wh[0][1]), "v"(wh[1][0]), "v"(wh[1][1]),
                           "v"(wh[2][0]), "v"(wh[2][1]), "v"(wh[3][0]), "v"(wh[3][1]));
        asm volatile("" :: "v"(wlo[0][0]), "v"(wlo[0][1]), "v"(wlo[1][0]), "v"(wlo[1][1]),
                           "v"(wlo[2][0]), "v"(wlo[2][1]), "v"(wlo[3][0]), "v"(wlo[3][1]));
        if (seg == 0) __syncthreads();
        const int tb = seg * 16384;
#pragma unroll
        for (int kk = 0; kk < 4; kk++) {
            bf16x8 a[4];
#pragma unroll
            for (int m = 0; m < 4; m++)
                a[m] = *(const bf16x8*)(lds + tb + (m * 4 + kk) * 1024 + l * 16);
#pragma unroll
            for (int f = 0; f < 2; f++)
#pragma unroll
                for (int m = 0; m < 4; m++) {
                    acc[m][f] = __builtin_amdgcn_mfma_f32_16x16x32_bf16(a[m], wh[kk][f], acc[m][f], 0, 0, 0);
                    acc[m][f] = __builtin_amdgcn_mfma_f32_16x16x32_bf16(a[m], wlo[kk][f], acc[m][f], 0, 0, 0);
                }
        }
    }

    float s1[2] = {0.f, 0.f}, s2[2] = {0.f, 0.f};
#pragma unroll
    for (int f = 0; f < 2; f++) {
        const int col = j0 + f * 16 + lr;
        const float bias = bl[col];
#pragma unroll
        for (int m = 0; m < 4; m++) {
#pragma unroll
            for (int r = 0; r < 4; r++) {
                int n = base + m * 16 + lg * 4 + r;
                if (n < N_NODES) {
                    float v = acc[m][f][r] + bias;
                    h[(size_t)n * D + col] = f32_to_bf16_rne(v);
                    s1[f] += v;
                    s2[f] += v * v;
                }
            }
        }
    }
#pragma unroll
    for (int f = 0; f < 2; f++) {
        s1[f] += __shfl_xor(s1[f], 16);
        s1[f] += __shfl_xor(s1[f], 32);
        s2[f] += __shfl_xor(s2[f], 16);
        s2[f] += __shfl_xor(s2[f], 32);
    }
    if (l < 16) {
        float* pp = partial + (size_t)blockIdx.x * 256;
        pp[j0 + l] = s1[0];
        pp[j0 + 16 + l] = s1[1];
        pp[128 + j0 + l] = s2[0];
        pp[128 + j0 + 16 + l] = s2[1];
    }
}

// reduce per-block partials -> bn32[32][256] (32 blocks — single-block version
// costs 106us on one CU, R14)
__global__ __launch_bounds__(256) void k_bnred(const float* __restrict__ partial, float* __restrict__ bn32) {
    int t = threadIdx.x;
    float s = 0.f;
    for (int b = blockIdx.x; b < N_GB; b += 32)
        s += partial[(size_t)b * 256 + t];
    bn32[blockIdx.x * 256 + t] = s;
}

// BN-apply + ReLU (+residual); coef computed per-block from bn32 (fused finalize).
// mode 0: out_hi = relu(bn(h)); mode 1: out_hi = xres + 0.5*relu(bn(h)); mode 2: out_f32 = relu(bn(h))
__global__ __launch_bounds__(256) void k_apply(const unsigned short* __restrict__ h,
                                               const float* __restrict__ bn32,
                                               const float* __restrict__ gamma, const float* __restrict__ beta,
                                               const unsigned short* __restrict__ xres_hi,
                                               unsigned short* __restrict__ out_hi,
                                               float* __restrict__ out_f32, int mode) {
    __shared__ float sa[128], sc[128];
    int t = threadIdx.x;
    if (t < 128) {
        float m1 = 0.f, m2 = 0.f;
#pragma unroll 8
        for (int i = 0; i < 32; i++) {
            m1 += bn32[i * 256 + t];
            m2 += bn32[i * 256 + 128 + t];
        }
        float mean = m1 * (1.0f / N_NODES);
        float var = m2 * (1.0f / N_NODES) - mean * mean;
        float inv = rsqrtf(var + BN_EPS);
        float av = gamma[t] * inv;
        sa[t] = av;
        sc[t] = beta[t] - mean * av;
    }
    __syncthreads();
    int idx = blockIdx.x * 256 + t;
    if (idx >= N_NODES * 32) return;
    int c0 = (idx & 31) * 4;
    uint2 hv = ((const uint2*)h)[idx];
    float r0 = fmaxf(fmaf(bf16lo_to_f32(hv.x), sa[c0], sc[c0]), 0.f);
    float r1 = fmaxf(fmaf(bf16hi_to_f32(hv.x), sa[c0 + 1], sc[c0 + 1]), 0.f);
    float r2 = fmaxf(fmaf(bf16lo_to_f32(hv.y), sa[c0 + 2], sc[c0 + 2]), 0.f);
    float r3 = fmaxf(fmaf(bf16hi_to_f32(hv.y), sa[c0 + 3], sc[c0 + 3]), 0.f);
    if (mode == 1) {
        uint2 xv = ((const uint2*)xres_hi)[idx];
        r0 = fmaf(0.5f, r0, bf16lo_to_f32(xv.x));
        r1 = fmaf(0.5f, r1, bf16hi_to_f32(xv.x));
        r2 = fmaf(0.5f, r2, bf16lo_to_f32(xv.y));
        r3 = fmaf(0.5f, r3, bf16hi_to_f32(xv.y));
    }
    if (mode == 2) {
        ((float4*)out_f32)[idx] = make_float4(r0, r1, r2, r3);
    } else {
        uint2 p;
        p.x = (unsigned)f32_to_bf16_rne(r0) | ((unsigned)f32_to_bf16_rne(r1) << 16);
        p.y = (unsigned)f32_to_bf16_rne(r2) | ((unsigned)f32_to_bf16_rne(r3) << 16);
        ((uint2*)out_hi)[idx] = p;
    }
}

// ---------------- launch ----------------

extern "C" void kernel_launch(void* const* d_in, const int* in_sizes, int n_in,
                              void* d_out, int out_size, void* d_ws, size_t ws_size,
                              hipStream_t stream) {
    const float* x_in = (const float*)d_in[0];
    const int* ei = (const int*)d_in[1];
    const float* Wl = (const float*)d_in[2];
    const float* bl = (const float*)d_in[3];
    const float* Wr = (const float*)d_in[4];
    const float* gamma = (const float*)d_in[5];
    const float* beta = (const float*)d_in[6];
    float* out = (float*)d_out;

    char* ws = (char*)d_ws;
    unsigned short* xhiA = (unsigned short*)ws; ws += (size_t)N_NODES * D * 2;
    unsigned short* xhiB = (unsigned short*)ws; ws += (size_t)N_NODES * D * 2;
    unsigned short* agghi = (unsigned short*)ws; ws += (size_t)N_NODES * D * 2;  // also h (aliased, safe)
    int* cursor = (int*)ws; ws += (size_t)N_NODES * 4;
    int* colidx = (int*)ws; ws += (size_t)N_NODES * CAP * 4;   // 19.2 MB buckets
    unsigned* pairbuf = (unsigned*)ws; ws += (size_t)NPART * PCAP * 4;  // 6.7 MB queues
    int* gcur = (int*)ws; ws += 64;
    unsigned short* wl_hi = (unsigned short*)ws; ws += (size_t)3 * D * D * 2;
    unsigned short* wl_lo = (unsigned short*)ws; ws += (size_t)3 * D * D * 2;
    unsigned short* wr_hi = (unsigned short*)ws; ws += (size_t)3 * D * D * 2;
    unsigned short* wr_lo = (unsigned short*)ws; ws += (size_t)3 * D * D * 2;
    float* partial = (float*)ws; ws += (size_t)N_GB * 256 * 4;
    float* bn32 = (float*)ws; ws += 32 * 256 * 4;

    const int* src = ei;
    const int* dst = ei + N_EDGES;

    k_prep<<<FILL_BLOCKS, 256, 0, stream>>>(x_in, Wl, Wr, xhiA, wl_hi, wl_lo, wr_hi, wr_lo, gcur);
    k_split<<<FILL_BLOCKS, 256, 0, stream>>>(src, dst, gcur, pairbuf);
    k_fill3<<<FILL3_BLOCKS, 256, 0, stream>>>(pairbuf, gcur, cursor, colidx);

    unsigned short* xin[3] = { xhiA, xhiB, xhiA };
    unsigned short* xout[3] = { xhiB, xhiA, (unsigned short*)0 };
    int mode[3] = { 0, 1, 2 };

    for (int i = 0; i < 3; i++) {
        k_agg<<<(N_NODES + 3) / 4, 256, 0, stream>>>(xin[i], cursor, colidx, agghi);
        k_gemm<<<N_GB, 256, 0, stream>>>(agghi, xin[i],
                                         wl_hi + (size_t)i * D * D, wl_lo + (size_t)i * D * D,
                                         wr_hi + (size_t)i * D * D, wr_lo + (size_t)i * D * D,
                                         bl + (size_t)i * D, agghi, partial);
        k_bnred<<<32, 256, 0, stream>>>(partial, bn32);
        k_apply<<<(N_NODES * 32 + 255) / 256, 256, 0, stream>>>(agghi, bn32,
                                                                gamma + (size_t)i * D, beta + (size_t)i * D,
                                                                xin[i], xout[i], out, mode[i]);
    }
}

// Round 19
// 499.181 us; speedup vs baseline: 1.3529x; 1.3529x over previous
//
#include <hip/hip_runtime.h>

#define N_NODES 100000
#define N_EDGES 1600000
#define D 128
#define BN_EPS 1e-5f
#define N_GB ((N_NODES + 63) / 64)      // 1563 gemm tiles
#define NPART 8
#define FILL_BLOCKS 2048
#define NODES_PER_PART (N_NODES / NPART)  // 12500 exact
#define CAP 48                            // bucket capacity: 192B = 3 lines; P(deg>48) ~ 8e-11/node

typedef short bf16x8 __attribute__((ext_vector_type(8)));
typedef float f32x4 __attribute__((ext_vector_type(4)));

__device__ inline unsigned short f32_to_bf16_rne(float f) {
    unsigned u = __builtin_bit_cast(unsigned, f);
    u += 0x7fffu + ((u >> 16) & 1u);
    return (unsigned short)(u >> 16);
}
__device__ inline float bf16lo_to_f32(unsigned v) { return __builtin_bit_cast(float, v << 16); }
__device__ inline float bf16hi_to_f32(unsigned v) { return __builtin_bit_cast(float, v & 0xffff0000u); }

__device__ inline void gload_lds16(const void* g, void* l) {
    __builtin_amdgcn_global_load_lds((const __attribute__((address_space(1))) unsigned*)g,
                                     (__attribute__((address_space(3))) unsigned*)l, 16, 0, 0);
}

// ---------------- prep: streaming conversions + cursor zeroing ----------------

__global__ __launch_bounds__(256) void k_prep(const float* __restrict__ x_in,
                                              const float* __restrict__ Wl, const float* __restrict__ Wr,
                                              unsigned short* __restrict__ xhi,
                                              unsigned short* __restrict__ wl_hi, unsigned short* __restrict__ wl_lo,
                                              unsigned short* __restrict__ wr_hi, unsigned short* __restrict__ wr_lo,
                                              int* __restrict__ cursor) {
    for (int idx = blockIdx.x * 256 + threadIdx.x; idx < N_NODES * 32; idx += FILL_BLOCKS * 256) {
        float4 v = ((const float4*)x_in)[idx];
        uint2 p;
        p.x = (unsigned)f32_to_bf16_rne(v.x) | ((unsigned)f32_to_bf16_rne(v.y) << 16);
        p.y = (unsigned)f32_to_bf16_rne(v.z) | ((unsigned)f32_to_bf16_rne(v.w) << 16);
        ((uint2*)xhi)[idx] = p;
    }
    for (int i = blockIdx.x * 256 + threadIdx.x; i < 2 * 3 * D * D; i += FILL_BLOCKS * 256) {
        const float* srcp = (i < 3 * D * D) ? Wl : Wr;
        int j = (i < 3 * D * D) ? i : i - 3 * D * D;
        float w = srcp[j];
        unsigned short h = f32_to_bf16_rne(w);
        float rem = w - bf16lo_to_f32((unsigned)h);
        if (i < 3 * D * D) { wl_hi[j] = h; wl_lo[j] = f32_to_bf16_rne(rem); }
        else               { wr_hi[j] = h; wr_lo[j] = f32_to_bf16_rne(rem); }
    }
    // zero cursor (replaces hipMemsetAsync dispatch)
    for (int i = blockIdx.x * 256 + threadIdx.x; i < N_NODES; i += FILL_BLOCKS * 256)
        cursor[i] = 0;
}

// ---------------- bucketed edge fill ----------------
// XCD-partitioned: partition p = blockIdx%8 owns dst range [p*12500,(p+1)*12500)
// so cursor atomics + colidx bucket lines stay XCD-local. Direct scatter —
// R17 (queue-split) and R18 (LDS-assembled full-line writes) both measured
// slower overall; this is the empirically best fill for this shape.
__global__ __launch_bounds__(256) void k_fill(const int* __restrict__ src, const int* __restrict__ dst,
                                              int* __restrict__ cursor, int* __restrict__ colidx) {
    const int part = blockIdx.x & (NPART - 1);
    const int lo = part * NODES_PER_PART;
    const int hi = lo + NODES_PER_PART;
    const int stride = (FILL_BLOCKS / NPART) * 256;
    for (int e = (blockIdx.x >> 3) * 256 + threadIdx.x; e < N_EDGES; e += stride) {
        int d = dst[e];
        if (d >= lo && d < hi) {
            int pos = atomicAdd(&cursor[d], 1);
            if (pos < CAP) colidx[d * CAP + pos] = src[e];  // guard keeps overflow non-corrupting
        }
    }
}

// ---------------- per-layer kernels ----------------

// mean aggregation: one wave per node (high occupancy — NOT fused with MFMA
// kernel per R10 lesson). colidx bucket register-cached, gathers uint4.
__global__ __launch_bounds__(256) void k_agg(const unsigned short* __restrict__ xhi,
                                             const int* __restrict__ cursor, const int* __restrict__ colidx,
                                             unsigned short* __restrict__ agghi) {
    const int wid = threadIdx.x >> 6;
    const int l = threadIdx.x & 63;
    const int n = blockIdx.x * 4 + wid;
    if (n >= N_NODES) return;
    const int degree = cursor[n];
    const int b = n * CAP;
    const int e = b + (degree < CAP ? degree : CAP);
    const int c8 = l & 15;   // 16B channel slice
    const int g = l >> 4;    // row-group 0..3
    const size_t coff = (size_t)c8 * 16;

    float acc[8];
#pragma unroll
    for (int k = 0; k < 8; k++) acc[k] = 0.f;

    int i = b;
    while (i < e) {
        int chunk = e - i; if (chunk > 64) chunk = 64;
        int myE = colidx[i + (l < chunk ? l : chunk - 1)];
        int j = 0;
        for (; j + 8 <= chunk; j += 8) {
            int s0 = __shfl(myE, j + g);
            int s1 = __shfl(myE, j + 4 + g);
            uint4 v0 = *(const uint4*)((const char*)xhi + (size_t)s0 * 256 + coff);
            uint4 v1 = *(const uint4*)((const char*)xhi + (size_t)s1 * 256 + coff);
            acc[0] += bf16lo_to_f32(v0.x); acc[1] += bf16hi_to_f32(v0.x);
            acc[2] += bf16lo_to_f32(v0.y); acc[3] += bf16hi_to_f32(v0.y);
            acc[4] += bf16lo_to_f32(v0.z); acc[5] += bf16hi_to_f32(v0.z);
            acc[6] += bf16lo_to_f32(v0.w); acc[7] += bf16hi_to_f32(v0.w);
            acc[0] += bf16lo_to_f32(v1.x); acc[1] += bf16hi_to_f32(v1.x);
            acc[2] += bf16lo_to_f32(v1.y); acc[3] += bf16hi_to_f32(v1.y);
            acc[4] += bf16lo_to_f32(v1.z); acc[5] += bf16hi_to_f32(v1.z);
            acc[6] += bf16lo_to_f32(v1.w); acc[7] += bf16hi_to_f32(v1.w);
        }
        for (; j + 4 <= chunk; j += 4) {
            int s0 = __shfl(myE, j + g);
            uint4 v0 = *(const uint4*)((const char*)xhi + (size_t)s0 * 256 + coff);
            acc[0] += bf16lo_to_f32(v0.x); acc[1] += bf16hi_to_f32(v0.x);
            acc[2] += bf16lo_to_f32(v0.y); acc[3] += bf16hi_to_f32(v0.y);
            acc[4] += bf16lo_to_f32(v0.z); acc[5] += bf16hi_to_f32(v0.z);
            acc[6] += bf16lo_to_f32(v0.w); acc[7] += bf16hi_to_f32(v0.w);
        }
        if (j < chunk) {
            int idx = j + g;
            int s0 = __shfl(myE, idx < chunk ? idx : chunk - 1);
            if (idx < chunk) {
                uint4 v0 = *(const uint4*)((const char*)xhi + (size_t)s0 * 256 + coff);
                acc[0] += bf16lo_to_f32(v0.x); acc[1] += bf16hi_to_f32(v0.x);
                acc[2] += bf16lo_to_f32(v0.y); acc[3] += bf16hi_to_f32(v0.y);
                acc[4] += bf16lo_to_f32(v0.z); acc[5] += bf16hi_to_f32(v0.z);
                acc[6] += bf16lo_to_f32(v0.w); acc[7] += bf16hi_to_f32(v0.w);
            }
        }
        i += chunk;
    }
#pragma unroll
    for (int k = 0; k < 8; k++) {
        acc[k] += __shfl_xor(acc[k], 16);
        acc[k] += __shfl_xor(acc[k], 32);
    }
    if (g == 0) {
        float idg = 1.0f / fmaxf((float)degree, 1.0f);
        uint4 p;
        p.x = (unsigned)f32_to_bf16_rne(acc[0] * idg) | ((unsigned)f32_to_bf16_rne(acc[1] * idg) << 16);
        p.y = (unsigned)f32_to_bf16_rne(acc[2] * idg) | ((unsigned)f32_to_bf16_rne(acc[3] * idg) << 16);
        p.z = (unsigned)f32_to_bf16_rne(acc[4] * idg) | ((unsigned)f32_to_bf16_rne(acc[5] * idg) << 16);
        p.w = (unsigned)f32_to_bf16_rne(acc[6] * idg) | ((unsigned)f32_to_bf16_rne(acc[7] * idg) << 16);
        *(uint4*)((char*)agghi + (size_t)n * 256 + coff) = p;
    }
}

// h(bf16) = agg @ Wl^T + bl + x @ Wr^T via MFMA.
// LDS tiles fragment-major (conflict-free); W frags pinned in VGPRs.
// BN partials per-block (no atomics). h aliases agg_hi (rows staged to LDS first).
__global__ __launch_bounds__(256, 2) void k_gemm(
    const unsigned short* __restrict__ agg_hi, const unsigned short* __restrict__ x_hi,
    const unsigned short* __restrict__ wl_hi, const unsigned short* __restrict__ wl_lo,
    const unsigned short* __restrict__ wr_hi, const unsigned short* __restrict__ wr_lo,
    const float* __restrict__ bl, unsigned short* __restrict__ h, float* __restrict__ partial) {
    __shared__ char lds[32768];  // 32 chunks x 1KB: [0..16K) agg frags, [16K..32K) x frags
    const int t = threadIdx.x;
    const int w = t >> 6;
    const int l = t & 63;
    const int lr = l & 15;
    const int lg = l >> 4;
    const int base = blockIdx.x * 64;
    const int j0 = w * 32;

    {
#pragma unroll
        for (int i = 0; i < 8; i++) {
            int c = w * 8 + i;
            int ci = c & 15;
            int m = ci >> 2, kk = ci & 3;
            int n = base + m * 16 + lr;
            if (n > N_NODES - 1) n = N_NODES - 1;
            size_t goff = (size_t)n * 256 + kk * 64 + lg * 16;
            const char* srcp = ((c & 16) ? (const char*)x_hi : (const char*)agg_hi) + goff;
            gload_lds16(srcp, lds + c * 1024);
        }
    }

    f32x4 acc[4][2];
#pragma unroll
    for (int m = 0; m < 4; m++)
#pragma unroll
        for (int f = 0; f < 2; f++) acc[m][f] = (f32x4){0.f, 0.f, 0.f, 0.f};

#pragma unroll
    for (int seg = 0; seg < 2; seg++) {
        const unsigned short* WH = seg ? wr_hi : wl_hi;
        const unsigned short* WLo = seg ? wr_lo : wl_lo;
        bf16x8 wh[4][2], wlo[4][2];
#pragma unroll
        for (int kk = 0; kk < 4; kk++)
#pragma unroll
            for (int f = 0; f < 2; f++) {
                size_t wo = (size_t)(j0 + f * 16 + lr) * D + kk * 32 + lg * 8;
                wh[kk][f] = *(const bf16x8*)(WH + wo);
                wlo[kk][f] = *(const bf16x8*)(WLo + wo);
            }
        asm volatile("" :: "v"(wh[0][0]), "v"(wh[0][1]), "v"(wh[1][0]), "v"(wh[1][1]),
                           "v"(wh[2][0]), "v"(wh[2][1]), "v"(wh[3][0]), "v"(wh[3][1]));
        asm volatile("" :: "v"(wlo[0][0]), "v"(wlo[0][1]), "v"(wlo[1][0]), "v"(wlo[1][1]),
                           "v"(wlo[2][0]), "v"(wlo[2][1]), "v"(wlo[3][0]), "v"(wlo[3][1]));
        if (seg == 0) __syncthreads();
        const int tb = seg * 16384;
#pragma unroll
        for (int kk = 0; kk < 4; kk++) {
            bf16x8 a[4];
#pragma unroll
            for (int m = 0; m < 4; m++)
                a[m] = *(const bf16x8*)(lds + tb + (m * 4 + kk) * 1024 + l * 16);
#pragma unroll
            for (int f = 0; f < 2; f++)
#pragma unroll
                for (int m = 0; m < 4; m++) {
                    acc[m][f] = __builtin_amdgcn_mfma_f32_16x16x32_bf16(a[m], wh[kk][f], acc[m][f], 0, 0, 0);
                    acc[m][f] = __builtin_amdgcn_mfma_f32_16x16x32_bf16(a[m], wlo[kk][f], acc[m][f], 0, 0, 0);
                }
        }
    }

    float s1[2] = {0.f, 0.f}, s2[2] = {0.f, 0.f};
#pragma unroll
    for (int f = 0; f < 2; f++) {
        const int col = j0 + f * 16 + lr;
        const float bias = bl[col];
#pragma unroll
        for (int m = 0; m < 4; m++) {
#pragma unroll
            for (int r = 0; r < 4; r++) {
                int n = base + m * 16 + lg * 4 + r;
                if (n < N_NODES) {
                    float v = acc[m][f][r] + bias;
                    h[(size_t)n * D + col] = f32_to_bf16_rne(v);
                    s1[f] += v;
                    s2[f] += v * v;
                }
            }
        }
    }
#pragma unroll
    for (int f = 0; f < 2; f++) {
        s1[f] += __shfl_xor(s1[f], 16);
        s1[f] += __shfl_xor(s1[f], 32);
        s2[f] += __shfl_xor(s2[f], 16);
        s2[f] += __shfl_xor(s2[f], 32);
    }
    if (l < 16) {
        float* pp = partial + (size_t)blockIdx.x * 256;
        pp[j0 + l] = s1[0];
        pp[j0 + 16 + l] = s1[1];
        pp[128 + j0 + l] = s2[0];
        pp[128 + j0 + 16 + l] = s2[1];
    }
}

// reduce per-block partials -> bn32[32][256] (32 blocks — single-block version
// costs 106us on one CU, R14)
__global__ __launch_bounds__(256) void k_bnred(const float* __restrict__ partial, float* __restrict__ bn32) {
    int t = threadIdx.x;
    float s = 0.f;
    for (int b = blockIdx.x; b < N_GB; b += 32)
        s += partial[(size_t)b * 256 + t];
    bn32[blockIdx.x * 256 + t] = s;
}

// BN-apply + ReLU (+residual); coef computed per-block from bn32 (fused finalize).
// mode 0: out_hi = relu(bn(h)); mode 1: out_hi = xres + 0.5*relu(bn(h)); mode 2: out_f32 = relu(bn(h))
__global__ __launch_bounds__(256) void k_apply(const unsigned short* __restrict__ h,
                                               const float* __restrict__ bn32,
                                               const float* __restrict__ gamma, const float* __restrict__ beta,
                                               const unsigned short* __restrict__ xres_hi,
                                               unsigned short* __restrict__ out_hi,
                                               float* __restrict__ out_f32, int mode) {
    __shared__ float sa[128], sc[128];
    int t = threadIdx.x;
    if (t < 128) {
        float m1 = 0.f, m2 = 0.f;
#pragma unroll 8
        for (int i = 0; i < 32; i++) {
            m1 += bn32[i * 256 + t];
            m2 += bn32[i * 256 + 128 + t];
        }
        float mean = m1 * (1.0f / N_NODES);
        float var = m2 * (1.0f / N_NODES) - mean * mean;
        float inv = rsqrtf(var + BN_EPS);
        float av = gamma[t] * inv;
        sa[t] = av;
        sc[t] = beta[t] - mean * av;
    }
    __syncthreads();
    int idx = blockIdx.x * 256 + t;
    if (idx >= N_NODES * 32) return;
    int c0 = (idx & 31) * 4;
    uint2 hv = ((const uint2*)h)[idx];
    float r0 = fmaxf(fmaf(bf16lo_to_f32(hv.x), sa[c0], sc[c0]), 0.f);
    float r1 = fmaxf(fmaf(bf16hi_to_f32(hv.x), sa[c0 + 1], sc[c0 + 1]), 0.f);
    float r2 = fmaxf(fmaf(bf16lo_to_f32(hv.y), sa[c0 + 2], sc[c0 + 2]), 0.f);
    float r3 = fmaxf(fmaf(bf16hi_to_f32(hv.y), sa[c0 + 3], sc[c0 + 3]), 0.f);
    if (mode == 1) {
        uint2 xv = ((const uint2*)xres_hi)[idx];
        r0 = fmaf(0.5f, r0, bf16lo_to_f32(xv.x));
        r1 = fmaf(0.5f, r1, bf16hi_to_f32(xv.x));
        r2 = fmaf(0.5f, r2, bf16lo_to_f32(xv.y));
        r3 = fmaf(0.5f, r3, bf16hi_to_f32(xv.y));
    }
    if (mode == 2) {
        ((float4*)out_f32)[idx] = make_float4(r0, r1, r2, r3);
    } else {
        uint2 p;
        p.x = (unsigned)f32_to_bf16_rne(r0) | ((unsigned)f32_to_bf16_rne(r1) << 16);
        p.y = (unsigned)f32_to_bf16_rne(r2) | ((unsigned)f32_to_bf16_rne(r3) << 16);
        ((uint2*)out_hi)[idx] = p;
    }
}

// ---------------- launch ----------------

extern "C" void kernel_launch(void* const* d_in, const int* in_sizes, int n_in,
                              void* d_out, int out_size, void* d_ws, size_t ws_size,
                              hipStream_t stream) {
    const float* x_in = (const float*)d_in[0];
    const int* ei = (const int*)d_in[1];
    const float* Wl = (const float*)d_in[2];
    const float* bl = (const float*)d_in[3];
    const float* Wr = (const float*)d_in[4];
    const float* gamma = (const float*)d_in[5];
    const float* beta = (const float*)d_in[6];
    float* out = (float*)d_out;

    char* ws = (char*)d_ws;
    unsigned short* xhiA = (unsigned short*)ws; ws += (size_t)N_NODES * D * 2;
    unsigned short* xhiB = (unsigned short*)ws; ws += (size_t)N_NODES * D * 2;
    unsigned short* agghi = (unsigned short*)ws; ws += (size_t)N_NODES * D * 2;  // also h (aliased, safe)
    int* cursor = (int*)ws; ws += (size_t)N_NODES * 4;
    int* colidx = (int*)ws; ws += (size_t)N_NODES * CAP * 4;   // 19.2 MB buckets
    unsigned short* wl_hi = (unsigned short*)ws; ws += (size_t)3 * D * D * 2;
    unsigned short* wl_lo = (unsigned short*)ws; ws += (size_t)3 * D * D * 2;
    unsigned short* wr_hi = (unsigned short*)ws; ws += (size_t)3 * D * D * 2;
    unsigned short* wr_lo = (unsigned short*)ws; ws += (size_t)3 * D * D * 2;
    float* partial = (float*)ws; ws += (size_t)N_GB * 256 * 4;
    float* bn32 = (float*)ws; ws += 32 * 256 * 4;

    const int* src = ei;
    const int* dst = ei + N_EDGES;

    k_prep<<<FILL_BLOCKS, 256, 0, stream>>>(x_in, Wl, Wr, xhiA, wl_hi, wl_lo, wr_hi, wr_lo, cursor);
    k_fill<<<FILL_BLOCKS, 256, 0, stream>>>(src, dst, cursor, colidx);

    unsigned short* xin[3] = { xhiA, xhiB, xhiA };
    unsigned short* xout[3] = { xhiB, xhiA, (unsigned short*)0 };
    int mode[3] = { 0, 1, 2 };

    for (int i = 0; i < 3; i++) {
        k_agg<<<(N_NODES + 3) / 4, 256, 0, stream>>>(xin[i], cursor, colidx, agghi);
        k_gemm<<<N_GB, 256, 0, stream>>>(agghi, xin[i],
                                         wl_hi + (size_t)i * D * D, wl_lo + (size_t)i * D * D,
                                         wr_hi + (size_t)i * D * D, wr_lo + (size_t)i * D * D,
                                         bl + (size_t)i * D, agghi, partial);
        k_bnred<<<32, 256, 0, stream>>>(partial, bn32);
        k_apply<<<(N_NODES * 32 + 255) / 256, 256, 0, stream>>>(agghi, bn32,
                                                                gamma + (size_t)i * D, beta + (size_t)i * D,
                                                                xin[i], xout[i], out, mode[i]);
    }
}